// Round 14
// baseline (433.525 us; speedup 1.0000x reference)
//
#include <hip/hip_runtime.h>
#include <hip/hip_bf16.h>

#define K_IN   1044
#define N_FEAT 128
#define KPAD2  1088   // 17 * 64
#define NST2   17
#define BM     96

#define NB     512    // coarse buckets for counting sort
#define BWMAX  256    // max nodes per bucket (runtime bw = ceil(N/NB) = 137)
#define EPB    8192   // edges per block in hist/stage

typedef __attribute__((ext_vector_type(8))) short short8;
typedef __attribute__((ext_vector_type(4))) float f32x4;

__device__ __forceinline__ ushort f2bf(float f) {
  unsigned x = __float_as_uint(f);
  x += 0x7fffu + ((x >> 16) & 1u);   // round-to-nearest-even
  return (ushort)(x >> 16);
}
// packed pair conversion: compiler lowers to v_cvt_pk_bf16_f32
__device__ __forceinline__ uint pkbf(float lo, float hi) {
  __hip_bfloat162 h = __float22bfloat162_rn(make_float2(lo, hi));
  return *reinterpret_cast<uint*>(&h);
}
__device__ __forceinline__ float bflo(uint v) { return __uint_as_float(v << 16); }
__device__ __forceinline__ float bfhi(uint v) { return __uint_as_float(v & 0xFFFF0000u); }

// async global->LDS, 16B per lane; dest = wave-uniform base + lane*16 (HW)
__device__ __forceinline__ void gld16(const void* g, void* l) {
  __builtin_amdgcn_global_load_lds(
      (const __attribute__((address_space(1))) unsigned int*)g,
      (__attribute__((address_space(3))) unsigned int*)l, 16, 0, 0);
}

// ================= merged: W1 convert + CSR bucket histogram =================
// blocks [0, convBlocks): W1 -> bf16 transposed [128][KPAD2], chunk-swizzled.
// blocks [convBlocks, ...): per-block bucket histogram of dst, written
// NON-atomically to pbc[bucket * eblocks + blk] (bucket-major for the scan).

__global__ __launch_bounds__(256) void convw1_hist_kernel(const float* __restrict__ W1,
                                                          ushort* __restrict__ W1T,
                                                          const int* __restrict__ dst,
                                                          int* __restrict__ pbc,
                                                          int E, int bw, int convBlocks,
                                                          int eblocks) {
  if ((int)blockIdx.x < convBlocks) {
    int idx = blockIdx.x * 256 + threadIdx.x;
    if (idx >= N_FEAT * KPAD2) return;
    int col = idx / KPAD2, k = idx - col * KPAD2;
    int kk = k & ~63;
    int jp = (k >> 3) & 7;
    int e  = k & 7;
    int jl = jp ^ (col & 7);
    int ksrc = kk + 8 * jl + e;
    W1T[idx] = (ksrc < K_IN) ? f2bf(W1[(size_t)ksrc * N_FEAT + col]) : (ushort)0;
  } else {
    __shared__ int h[NB];
    const int t = threadIdx.x;
    const int blk = blockIdx.x - convBlocks;
    for (int i = t; i < NB; i += 256) h[i] = 0;
    __syncthreads();
    const int e0 = blk * EPB;
    const int e1 = min(e0 + EPB, E);
    for (int e = e0 + t; e < e1; e += 256) atomicAdd(&h[dst[e] / bw], 1);
    __syncthreads();
    for (int i = t; i < NB; i += 256) pbc[i * eblocks + blk] = h[i];
  }
}

// single-block exclusive scan of pbc[NB*eblocks] (bucket-major) in place.
// Also emits bucket_base[b] = prefix at (b,0) and bucket_base[NB] = E.
__global__ __launch_bounds__(256) void csr_scan2_kernel(int* __restrict__ pbc,
                                                        int* __restrict__ bucket_base,
                                                        int eblocks, int total, int E) {
  __shared__ int sums[256];
  const int t = threadIdx.x;
  const int chunk = (total + 255) / 256;
  const int beg = t * chunk;
  const int end = min(beg + chunk, total);
  int s = 0;
  for (int i = beg; i < end; i++) s += pbc[i];
  sums[t] = s;
  __syncthreads();
  for (int off = 1; off < 256; off <<= 1) {
    int x = (t >= off) ? sums[t - off] : 0;
    __syncthreads();
    sums[t] += x;
    __syncthreads();
  }
  int run = sums[t] - s;   // exclusive prefix of this thread's chunk
  for (int i = beg; i < end; i++) {
    int v = pbc[i];
    pbc[i] = run;
    if (i % eblocks == 0) bucket_base[i / eblocks] = run;
    run += v;
  }
  if (t == 255) bucket_base[NB] = E;
}

// staging entry: (src << 8) | (dst - bucket*bw), bw=137 < 256.
// Per-block bases come precomputed from pbc -- no histogram pass, no global atomics.
__global__ __launch_bounds__(256) void csr_stage_kernel(const int* __restrict__ src,
                                                        const int* __restrict__ dst,
                                                        const int* __restrict__ pbc,
                                                        uint* __restrict__ staging, int E, int bw,
                                                        int eblocks) {
  __shared__ int cur[NB];
  const int t = threadIdx.x;
  const int blk = blockIdx.x;
  for (int i = t; i < NB; i += 256) cur[i] = pbc[i * eblocks + blk];
  __syncthreads();
  const int e0 = blk * EPB;
  const int e1 = min(e0 + EPB, E);
  for (int e = e0 + t; e < e1; e += 256) {
    int d = dst[e];
    int b = d / bw;
    int p = atomicAdd(&cur[b], 1);
    staging[p] = ((uint)src[e] << 8) | (uint)(d - b * bw);
  }
}

// one block per bucket: node histogram + scan + scatter -> row_ptr, sorted_src, dinv
__global__ __launch_bounds__(256) void csr_final_kernel(const uint* __restrict__ staging,
                                                        const int* __restrict__ bucket_base,
                                                        int* __restrict__ row_ptr,
                                                        int* __restrict__ sorted_src,
                                                        float* __restrict__ dinv,
                                                        int N, int bw, int E) {
  __shared__ int hist[BWMAX];
  __shared__ int sc[256];
  const int b = blockIdx.x;
  const int t = threadIdx.x;
  if (b == 0 && t == 0) row_ptr[N] = E;
  const int node0 = b * bw;
  const int nn = min(bw, N - node0);
  if (nn <= 0) return;
  const int base = bucket_base[b];
  const int cnt  = bucket_base[b + 1] - base;

  for (int i = t; i < BWMAX; i += 256) hist[i] = 0;
  __syncthreads();
  for (int i = t; i < cnt; i += 256)
    atomicAdd(&hist[staging[base + i] & 255u], 1);
  __syncthreads();
  int v = (t < nn) ? hist[t] : 0;
  if (t < nn) dinv[node0 + t] = rsqrtf((float)(v + 1));   // +1 self-loop
  sc[t] = v;
  __syncthreads();
  for (int off = 1; off < 256; off <<= 1) {
    int x = (t >= off) ? sc[t - off] : 0;
    __syncthreads();
    sc[t] += x;
    __syncthreads();
  }
  int excl = sc[t] - v;
  if (t < nn) row_ptr[node0 + t] = base + excl;
  if (t < nn) hist[t] = excl;   // reuse as cursors
  __syncthreads();
  for (int i = t; i < cnt; i += 256) {
    uint p = staging[base + i];
    int c = atomicAdd(&hist[p & 255u], 1);
    sorted_src[base + c] = (int)(p >> 8);
  }
}

// ---------------- layer 1 GEMM (MFMA bf16): g1 = dinv * (X @ W1), stored bf16 ----------------
// BM=96, BN=128, BK=64 staging; 4 waves (2x2), wave tile 48x64.
// Both tiles via global_load_lds, double-buffered, one __syncthreads per stage.

__global__ __launch_bounds__(256) void gemm1_mfma_kernel(const float* __restrict__ X,
                                                         const ushort* __restrict__ W1T,
                                                         const float* __restrict__ dinv,
                                                         ushort* __restrict__ G1, int M) {
  __shared__ float  Af[2][BM * 64];      // 2 x 24 KB
  __shared__ ushort Bsb[2][128 * 64];    // 2 x 16 KB   (total 80 KB -> 2 blocks/CU)

  const int t = threadIdx.x;
  const int row0 = blockIdx.x * BM;
  const int w = t >> 6, l = t & 63;
  const int w24 = w * 24, w32 = w * 32;
  const int Mm1 = M - 1;

  const int wm = w >> 1, wn = w & 1;
  const int lr = l & 15, g = l >> 4;

  f32x4 acc[3][4] = {};

  auto stage = [&](int s, int buf) {
    const int kk = s * 64;
    #pragma unroll
    for (int i = 0; i < 6; i++) {
      int r  = w24 + 4 * i + (l >> 4);
      int jl = (l & 15) ^ (r & 15);
      int grow = min(row0 + r, Mm1);
      int gk   = min(kk + 4 * jl, K_IN - 4);
      gld16(X + (size_t)grow * K_IN + gk, (void*)&Af[buf][(w24 + 4 * i) * 64]);
    }
    #pragma unroll
    for (int i = 0; i < 4; i++) {
      int c = w32 + 8 * i + (l >> 3);
      gld16(W1T + (size_t)c * KPAD2 + kk + 8 * (l & 7),
            (void*)&Bsb[buf][(w32 + 8 * i) * 64]);
    }
  };

  stage(0, 0);
  __syncthreads();

  int cur = 0;
  #pragma unroll 1
  for (int s = 0; s < NST2; s++) {
    if (s + 1 < NST2) stage(s + 1, cur ^ 1);   // async into other buffer

    #pragma unroll
    for (int ss = 0; ss < 2; ss++) {
      short8 af[3], bfr[4];
      #pragma unroll
      for (int m = 0; m < 3; m++) {
        const int row = wm * 48 + m * 16 + lr;
        const float* rp = &Af[cur][row * 64];
        const int c0 = (ss * 8 + 2 * g)     ^ (row & 15);
        const int c1 = (ss * 8 + 2 * g + 1) ^ (row & 15);
        float4 a0 = *(const float4*)&rp[c0 * 4];
        float4 a1 = *(const float4*)&rp[c1 * 4];
        uint4 uu = make_uint4(pkbf(a0.x, a0.y), pkbf(a0.z, a0.w),
                              pkbf(a1.x, a1.y), pkbf(a1.z, a1.w));
        af[m] = *(short8*)&uu;
      }
      #pragma unroll
      for (int n = 0; n < 4; n++) {
        const int col = wn * 64 + n * 16 + lr;
        const int cB = (ss * 4 + g) ^ (col & 7);
        bfr[n] = *(const short8*)&Bsb[cur][col * 64 + cB * 8];
      }
      #pragma unroll
      for (int m = 0; m < 3; m++)
        #pragma unroll
        for (int n = 0; n < 4; n++)
          acc[m][n] = __builtin_amdgcn_mfma_f32_16x16x32_bf16(af[m], bfr[n], acc[m][n], 0, 0, 0);
    }

    __syncthreads();   // next stage landed; reads of cur done
    cur ^= 1;
  }

  const int rbase = row0 + wm * 48 + g * 4;
  const int cbase = wn * 64 + lr;
  #pragma unroll
  for (int m = 0; m < 3; m++) {
    #pragma unroll
    for (int r = 0; r < 4; r++) {
      int row = rbase + m * 16 + r;
      if (row < M) {
        float dv = dinv[row];
        #pragma unroll
        for (int n = 0; n < 4; n++)
          G1[(size_t)row * N_FEAT + cbase + n * 16] = f2bf(dv * acc[m][n][r]);
      }
    }
  }
}

// ---------------- fused layer-1 aggregation + layer-2 GEMM ----------------

__global__ __launch_bounds__(256) void agg1mm_kernel(const ushort* __restrict__ G1,
                                                     const int* __restrict__ row_ptr,
                                                     const int* __restrict__ sorted_src,
                                                     const float* __restrict__ dinv,
                                                     const float* __restrict__ b1,
                                                     const float* __restrict__ W2,  // [128][3]
                                                     float* __restrict__ G2, int N) {
  const int w = (blockIdx.x * blockDim.x + threadIdx.x) >> 6;   // node
  const int lane = threadIdx.x & 63;
  if (w >= N) return;
  const int beg = row_ptr[w], end = row_ptr[w + 1];
  const uint* g1u = (const uint*)G1;
  const int co = lane;

  uint vs = g1u[((size_t)w << 6) + co];
  float a0 = bflo(vs), a1 = bfhi(vs);

  int e = beg;
  for (; e + 16 <= end; e += 16) {
    int s[16];
    #pragma unroll
    for (int i = 0; i < 16; i++) s[i] = sorted_src[e + i];
    uint v[16];
    #pragma unroll
    for (int i = 0; i < 16; i++) v[i] = g1u[((size_t)s[i] << 6) + co];
    #pragma unroll
    for (int i = 0; i < 16; i++) { a0 += bflo(v[i]); a1 += bfhi(v[i]); }
  }
  for (; e + 4 <= end; e += 4) {
    int s[4];
    #pragma unroll
    for (int i = 0; i < 4; i++) s[i] = sorted_src[e + i];
    uint v[4];
    #pragma unroll
    for (int i = 0; i < 4; i++) v[i] = g1u[((size_t)s[i] << 6) + co];
    #pragma unroll
    for (int i = 0; i < 4; i++) { a0 += bflo(v[i]); a1 += bfhi(v[i]); }
  }
  for (; e < end; e++) {
    uint v = g1u[((size_t)sorted_src[e] << 6) + co];
    a0 += bflo(v); a1 += bfhi(v);
  }

  const float di = dinv[w];
  float r0 = fmaxf(fmaf(di, a0, b1[2 * co + 0]), 0.f);
  float r1 = fmaxf(fmaf(di, a1, b1[2 * co + 1]), 0.f);

  const float* wrow = W2 + 6 * co;
  float s0 = r0 * wrow[0] + r1 * wrow[3];
  float s1 = r0 * wrow[1] + r1 * wrow[4];
  float s2 = r0 * wrow[2] + r1 * wrow[5];
  #pragma unroll
  for (int off = 32; off > 0; off >>= 1) {
    s0 += __shfl_down(s0, off);
    s1 += __shfl_down(s1, off);
    s2 += __shfl_down(s2, off);
  }
  if (lane == 0) {
    *(float4*)&G2[(size_t)w * 4] = make_float4(di * s0, di * s1, di * s2, 0.f);
  }
}

// ---------------- layer 2 aggregation: 2 nodes per wave (32 lanes each) ----------------

__global__ __launch_bounds__(256) void agg2_kernel(const float* __restrict__ G2,  // [N][4]
                                                   const int* __restrict__ row_ptr,
                                                   const int* __restrict__ sorted_src,
                                                   const float* __restrict__ dinv,
                                                   const float* __restrict__ b2,
                                                   float* __restrict__ out, int N) {
  int t = blockIdx.x * blockDim.x + threadIdx.x;
  int node = t >> 5, lane = t & 31;
  if (node >= N) return;
  int beg = row_ptr[node], end = row_ptr[node + 1];
  float a0 = 0.f, a1 = 0.f, a2 = 0.f;
  for (int e = beg + lane; e < end; e += 32) {
    float4 v = *(const float4*)&G2[(size_t)sorted_src[e] * 4];
    a0 += v.x; a1 += v.y; a2 += v.z;
  }
  #pragma unroll
  for (int off = 16; off > 0; off >>= 1) {
    a0 += __shfl_down(a0, off, 32);
    a1 += __shfl_down(a1, off, 32);
    a2 += __shfl_down(a2, off, 32);
  }
  if (lane == 0) {
    float di = dinv[node];
    float4 self = *(const float4*)&G2[(size_t)node * 4];
    out[node * 3 + 0] = di * (a0 + self.x) + b2[0];
    out[node * 3 + 1] = di * (a1 + self.y) + b2[1];
    out[node * 3 + 2] = di * (a2 + self.z) + b2[2];
  }
}

// ---------------- launch ----------------

extern "C" void kernel_launch(void* const* d_in, const int* in_sizes, int n_in,
                              void* d_out, int out_size, void* d_ws, size_t ws_size,
                              hipStream_t stream) {
  const float* features = (const float*)d_in[0];
  const int*   edges    = (const int*)d_in[1];
  const float* W1 = (const float*)d_in[4];
  const float* b1 = (const float*)d_in[5];
  const float* W2 = (const float*)d_in[6];
  const float* b2 = (const float*)d_in[7];
  float* out = (float*)d_out;

  const int N = in_sizes[0] / K_IN;   // 70000
  const int E = in_sizes[1] / 2;      // 2,000,000
  const int* src = edges;
  const int* dst = edges + E;
  const int bw = (N + NB - 1) / NB;   // 137

  char* ws = (char*)d_ws;
  size_t off = 0;
  auto alloc = [&](size_t bytes) {
    void* p = ws + off;
    off += (bytes + 255) & ~(size_t)255;
    return p;
  };
  const int eblocks = (E + EPB - 1) / EPB;

  int*    pbc           = (int*)   alloc((size_t)NB * eblocks * sizeof(int));
  int*    bucket_base   = (int*)   alloc((size_t)(NB + 1) * sizeof(int));
  int*    row_ptr       = (int*)   alloc((size_t)(N + 1) * sizeof(int));
  float*  dinv          = (float*) alloc((size_t)N * sizeof(float));
  uint*   staging       = (uint*)  alloc((size_t)E * sizeof(uint));
  int*    sorted_src    = (int*)   alloc((size_t)E * sizeof(int));
  ushort* G1            = (ushort*)alloc((size_t)N * N_FEAT * sizeof(ushort));
  float*  G2            = (float*) alloc((size_t)N * 4 * sizeof(float));
  ushort* W1T           = (ushort*)alloc((size_t)N_FEAT * KPAD2 * sizeof(ushort));
  (void)ws_size;

  const int convBlocks = (N_FEAT * KPAD2 + 255) / 256;

  convw1_hist_kernel<<<convBlocks + eblocks, 256, 0, stream>>>(W1, W1T, dst, pbc, E, bw, convBlocks, eblocks);
  csr_scan2_kernel<<<1, 256, 0, stream>>>(pbc, bucket_base, eblocks, NB * eblocks, E);
  csr_stage_kernel<<<eblocks, 256, 0, stream>>>(src, dst, pbc, staging, E, bw, eblocks);
  csr_final_kernel<<<NB, 256, 0, stream>>>(staging, bucket_base, row_ptr, sorted_src, dinv, N, bw, E);
  gemm1_mfma_kernel<<<(N + BM - 1) / BM, 256, 0, stream>>>(features, W1T, dinv, G1, N);
  agg1mm_kernel<<<((size_t)N * 64 + 255) / 256, 256, 0, stream>>>(G1, row_ptr, sorted_src, dinv, b1, W2, G2, N);
  agg2_kernel<<<((size_t)N * 32 + 255) / 256, 256, 0, stream>>>(G2, row_ptr, sorted_src, dinv, b2, out, N);
}

// Round 15
// 236.220 us; speedup vs baseline: 1.8353x; 1.8353x over previous
//
#include <hip/hip_runtime.h>
#include <hip/hip_bf16.h>

#define K_IN   1044
#define N_FEAT 128
#define KPAD2  1088   // 17 * 64
#define NST2   17
#define BM     96

#define NB     512    // coarse buckets for counting sort
#define BWMAX  256    // max nodes per bucket (runtime bw = ceil(N/NB) = 137)
#define EPB    8192   // edges per block in hist/stage (eblocks = 245 <= 256!)

typedef __attribute__((ext_vector_type(8))) short short8;
typedef __attribute__((ext_vector_type(4))) float f32x4;

__device__ __forceinline__ ushort f2bf(float f) {
  unsigned x = __float_as_uint(f);
  x += 0x7fffu + ((x >> 16) & 1u);   // round-to-nearest-even
  return (ushort)(x >> 16);
}
// packed pair conversion: compiler lowers to v_cvt_pk_bf16_f32
__device__ __forceinline__ uint pkbf(float lo, float hi) {
  __hip_bfloat162 h = __float22bfloat162_rn(make_float2(lo, hi));
  return *reinterpret_cast<uint*>(&h);
}
__device__ __forceinline__ float bflo(uint v) { return __uint_as_float(v << 16); }
__device__ __forceinline__ float bfhi(uint v) { return __uint_as_float(v & 0xFFFF0000u); }

// async global->LDS, 16B per lane; dest = wave-uniform base + lane*16 (HW)
__device__ __forceinline__ void gld16(const void* g, void* l) {
  __builtin_amdgcn_global_load_lds(
      (const __attribute__((address_space(1))) unsigned int*)g,
      (__attribute__((address_space(3))) unsigned int*)l, 16, 0, 0);
}

// ================= merged: W1 convert + CSR bucket histogram =================
// blocks [0, convBlocks): W1 -> bf16 transposed [128][KPAD2], chunk-swizzled.
// blocks [convBlocks, ...): per-block bucket histogram of dst, written
// NON-atomically to pbc[bucket * eblocks + blk] (bucket-major).

__global__ __launch_bounds__(256) void convw1_hist_kernel(const float* __restrict__ W1,
                                                          ushort* __restrict__ W1T,
                                                          const int* __restrict__ dst,
                                                          int* __restrict__ pbc,
                                                          int E, int bw, int convBlocks,
                                                          int eblocks) {
  if ((int)blockIdx.x < convBlocks) {
    int idx = blockIdx.x * 256 + threadIdx.x;
    if (idx >= N_FEAT * KPAD2) return;
    int col = idx / KPAD2, k = idx - col * KPAD2;
    int kk = k & ~63;
    int jp = (k >> 3) & 7;
    int e  = k & 7;
    int jl = jp ^ (col & 7);
    int ksrc = kk + 8 * jl + e;
    W1T[idx] = (ksrc < K_IN) ? f2bf(W1[(size_t)ksrc * N_FEAT + col]) : (ushort)0;
  } else {
    __shared__ int h[NB];
    const int t = threadIdx.x;
    const int blk = blockIdx.x - convBlocks;
    for (int i = t; i < NB; i += 256) h[i] = 0;
    __syncthreads();
    const int e0 = blk * EPB;
    const int e1 = min(e0 + EPB, E);
    for (int e = e0 + t; e < e1; e += 256) atomicAdd(&h[dst[e] / bw], 1);
    __syncthreads();
    for (int i = t; i < NB; i += 256) pbc[i * eblocks + blk] = h[i];
  }
}

// S1: one block per bucket: exclusive scan of pbc[b][0..eblocks) in LDS (eblocks<=256),
// in-place within-bucket prefixes; bucket total -> bt[b].
__global__ __launch_bounds__(256) void csr_scan_bucket_kernel(int* __restrict__ pbc,
                                                              int* __restrict__ bt,
                                                              int eblocks) {
  __shared__ int sc[256];
  const int b = blockIdx.x;
  const int t = threadIdx.x;
  int v = (t < eblocks) ? pbc[(size_t)b * eblocks + t] : 0;
  sc[t] = v;
  __syncthreads();
  for (int off = 1; off < 256; off <<= 1) {
    int x = (t >= off) ? sc[t - off] : 0;
    __syncthreads();
    sc[t] += x;
    __syncthreads();
  }
  if (t < eblocks) pbc[(size_t)b * eblocks + t] = sc[t] - v;   // exclusive
  if (t == 255) bt[b] = sc[255];
}

// S2: single block: exclusive scan of bt[NB] -> bucket_base[NB+1]
__global__ __launch_bounds__(256) void csr_bucket_scan_kernel(const int* __restrict__ bt,
                                                              int* __restrict__ bucket_base) {
  __shared__ int sc[256];
  const int t = threadIdx.x;
  int v0 = bt[2 * t], v1 = bt[2 * t + 1];
  int s = v0 + v1;
  sc[t] = s;
  __syncthreads();
  for (int off = 1; off < 256; off <<= 1) {
    int x = (t >= off) ? sc[t - off] : 0;
    __syncthreads();
    sc[t] += x;
    __syncthreads();
  }
  int excl = sc[t] - s;
  bucket_base[2 * t]     = excl;
  bucket_base[2 * t + 1] = excl + v0;
  if (t == 255) bucket_base[NB] = sc[255];
}

// staging entry: (src << 8) | (dst - bucket*bw), bw=137 < 256.
// cur[i] = bucket_base[i] + within-bucket prefix for this block (deterministic).
__global__ __launch_bounds__(256) void csr_stage_kernel(const int* __restrict__ src,
                                                        const int* __restrict__ dst,
                                                        const int* __restrict__ pbc,
                                                        const int* __restrict__ bucket_base,
                                                        uint* __restrict__ staging, int E, int bw,
                                                        int eblocks) {
  __shared__ int cur[NB];
  const int t = threadIdx.x;
  const int blk = blockIdx.x;
  for (int i = t; i < NB; i += 256)
    cur[i] = bucket_base[i] + pbc[(size_t)i * eblocks + blk];
  __syncthreads();
  const int e0 = blk * EPB;
  const int e1 = min(e0 + EPB, E);
  for (int e = e0 + t; e < e1; e += 256) {
    int d = dst[e];
    int b = d / bw;
    int p = atomicAdd(&cur[b], 1);
    staging[p] = ((uint)src[e] << 8) | (uint)(d - b * bw);
  }
}

// one block per bucket: node histogram + scan + scatter -> row_ptr, sorted_src, dinv
__global__ __launch_bounds__(256) void csr_final_kernel(const uint* __restrict__ staging,
                                                        const int* __restrict__ bucket_base,
                                                        int* __restrict__ row_ptr,
                                                        int* __restrict__ sorted_src,
                                                        float* __restrict__ dinv,
                                                        int N, int bw, int E) {
  __shared__ int hist[BWMAX];
  __shared__ int sc[256];
  const int b = blockIdx.x;
  const int t = threadIdx.x;
  if (b == 0 && t == 0) row_ptr[N] = E;
  const int node0 = b * bw;
  const int nn = min(bw, N - node0);
  if (nn <= 0) return;
  const int base = bucket_base[b];
  const int cnt  = bucket_base[b + 1] - base;

  for (int i = t; i < BWMAX; i += 256) hist[i] = 0;
  __syncthreads();
  for (int i = t; i < cnt; i += 256)
    atomicAdd(&hist[staging[base + i] & 255u], 1);
  __syncthreads();
  int v = (t < nn) ? hist[t] : 0;
  if (t < nn) dinv[node0 + t] = rsqrtf((float)(v + 1));   // +1 self-loop
  sc[t] = v;
  __syncthreads();
  for (int off = 1; off < 256; off <<= 1) {
    int x = (t >= off) ? sc[t - off] : 0;
    __syncthreads();
    sc[t] += x;
    __syncthreads();
  }
  int excl = sc[t] - v;
  if (t < nn) row_ptr[node0 + t] = base + excl;
  if (t < nn) hist[t] = excl;   // reuse as cursors
  __syncthreads();
  for (int i = t; i < cnt; i += 256) {
    uint p = staging[base + i];
    int c = atomicAdd(&hist[p & 255u], 1);
    sorted_src[base + c] = (int)(p >> 8);
  }
}

// ---------------- layer 1 GEMM (MFMA bf16): g1 = dinv * (X @ W1), stored bf16 ----------------
// BM=96, BN=128, BK=64 staging; 4 waves (2x2), wave tile 48x64.
// Both tiles via global_load_lds, double-buffered, one __syncthreads per stage.

__global__ __launch_bounds__(256) void gemm1_mfma_kernel(const float* __restrict__ X,
                                                         const ushort* __restrict__ W1T,
                                                         const float* __restrict__ dinv,
                                                         ushort* __restrict__ G1, int M) {
  __shared__ float  Af[2][BM * 64];      // 2 x 24 KB
  __shared__ ushort Bsb[2][128 * 64];    // 2 x 16 KB   (total 80 KB -> 2 blocks/CU)

  const int t = threadIdx.x;
  const int row0 = blockIdx.x * BM;
  const int w = t >> 6, l = t & 63;
  const int w24 = w * 24, w32 = w * 32;
  const int Mm1 = M - 1;

  const int wm = w >> 1, wn = w & 1;
  const int lr = l & 15, g = l >> 4;

  f32x4 acc[3][4] = {};

  auto stage = [&](int s, int buf) {
    const int kk = s * 64;
    #pragma unroll
    for (int i = 0; i < 6; i++) {
      int r  = w24 + 4 * i + (l >> 4);
      int jl = (l & 15) ^ (r & 15);
      int grow = min(row0 + r, Mm1);
      int gk   = min(kk + 4 * jl, K_IN - 4);
      gld16(X + (size_t)grow * K_IN + gk, (void*)&Af[buf][(w24 + 4 * i) * 64]);
    }
    #pragma unroll
    for (int i = 0; i < 4; i++) {
      int c = w32 + 8 * i + (l >> 3);
      gld16(W1T + (size_t)c * KPAD2 + kk + 8 * (l & 7),
            (void*)&Bsb[buf][(w32 + 8 * i) * 64]);
    }
  };

  stage(0, 0);
  __syncthreads();

  int cur = 0;
  #pragma unroll 1
  for (int s = 0; s < NST2; s++) {
    if (s + 1 < NST2) stage(s + 1, cur ^ 1);   // async into other buffer

    #pragma unroll
    for (int ss = 0; ss < 2; ss++) {
      short8 af[3], bfr[4];
      #pragma unroll
      for (int m = 0; m < 3; m++) {
        const int row = wm * 48 + m * 16 + lr;
        const float* rp = &Af[cur][row * 64];
        const int c0 = (ss * 8 + 2 * g)     ^ (row & 15);
        const int c1 = (ss * 8 + 2 * g + 1) ^ (row & 15);
        float4 a0 = *(const float4*)&rp[c0 * 4];
        float4 a1 = *(const float4*)&rp[c1 * 4];
        uint4 uu = make_uint4(pkbf(a0.x, a0.y), pkbf(a0.z, a0.w),
                              pkbf(a1.x, a1.y), pkbf(a1.z, a1.w));
        af[m] = *(short8*)&uu;
      }
      #pragma unroll
      for (int n = 0; n < 4; n++) {
        const int col = wn * 64 + n * 16 + lr;
        const int cB = (ss * 4 + g) ^ (col & 7);
        bfr[n] = *(const short8*)&Bsb[cur][col * 64 + cB * 8];
      }
      #pragma unroll
      for (int m = 0; m < 3; m++)
        #pragma unroll
        for (int n = 0; n < 4; n++)
          acc[m][n] = __builtin_amdgcn_mfma_f32_16x16x32_bf16(af[m], bfr[n], acc[m][n], 0, 0, 0);
    }

    __syncthreads();   // next stage landed; reads of cur done
    cur ^= 1;
  }

  const int rbase = row0 + wm * 48 + g * 4;
  const int cbase = wn * 64 + lr;
  #pragma unroll
  for (int m = 0; m < 3; m++) {
    #pragma unroll
    for (int r = 0; r < 4; r++) {
      int row = rbase + m * 16 + r;
      if (row < M) {
        float dv = dinv[row];
        #pragma unroll
        for (int n = 0; n < 4; n++)
          G1[(size_t)row * N_FEAT + cbase + n * 16] = f2bf(dv * acc[m][n][r]);
      }
    }
  }
}

// ---------------- fused layer-1 aggregation + layer-2 GEMM ----------------

__global__ __launch_bounds__(256) void agg1mm_kernel(const ushort* __restrict__ G1,
                                                     const int* __restrict__ row_ptr,
                                                     const int* __restrict__ sorted_src,
                                                     const float* __restrict__ dinv,
                                                     const float* __restrict__ b1,
                                                     const float* __restrict__ W2,  // [128][3]
                                                     float* __restrict__ G2, int N) {
  const int w = (blockIdx.x * blockDim.x + threadIdx.x) >> 6;   // node
  const int lane = threadIdx.x & 63;
  if (w >= N) return;
  const int beg = row_ptr[w], end = row_ptr[w + 1];
  const uint* g1u = (const uint*)G1;
  const int co = lane;

  uint vs = g1u[((size_t)w << 6) + co];
  float a0 = bflo(vs), a1 = bfhi(vs);

  int e = beg;
  for (; e + 16 <= end; e += 16) {
    int s[16];
    #pragma unroll
    for (int i = 0; i < 16; i++) s[i] = sorted_src[e + i];
    uint v[16];
    #pragma unroll
    for (int i = 0; i < 16; i++) v[i] = g1u[((size_t)s[i] << 6) + co];
    #pragma unroll
    for (int i = 0; i < 16; i++) { a0 += bflo(v[i]); a1 += bfhi(v[i]); }
  }
  for (; e + 4 <= end; e += 4) {
    int s[4];
    #pragma unroll
    for (int i = 0; i < 4; i++) s[i] = sorted_src[e + i];
    uint v[4];
    #pragma unroll
    for (int i = 0; i < 4; i++) v[i] = g1u[((size_t)s[i] << 6) + co];
    #pragma unroll
    for (int i = 0; i < 4; i++) { a0 += bflo(v[i]); a1 += bfhi(v[i]); }
  }
  for (; e < end; e++) {
    uint v = g1u[((size_t)sorted_src[e] << 6) + co];
    a0 += bflo(v); a1 += bfhi(v);
  }

  const float di = dinv[w];
  float r0 = fmaxf(fmaf(di, a0, b1[2 * co + 0]), 0.f);
  float r1 = fmaxf(fmaf(di, a1, b1[2 * co + 1]), 0.f);

  const float* wrow = W2 + 6 * co;
  float s0 = r0 * wrow[0] + r1 * wrow[3];
  float s1 = r0 * wrow[1] + r1 * wrow[4];
  float s2 = r0 * wrow[2] + r1 * wrow[5];
  #pragma unroll
  for (int off = 32; off > 0; off >>= 1) {
    s0 += __shfl_down(s0, off);
    s1 += __shfl_down(s1, off);
    s2 += __shfl_down(s2, off);
  }
  if (lane == 0) {
    *(float4*)&G2[(size_t)w * 4] = make_float4(di * s0, di * s1, di * s2, 0.f);
  }
}

// ---------------- layer 2 aggregation: 2 nodes per wave (32 lanes each) ----------------

__global__ __launch_bounds__(256) void agg2_kernel(const float* __restrict__ G2,  // [N][4]
                                                   const int* __restrict__ row_ptr,
                                                   const int* __restrict__ sorted_src,
                                                   const float* __restrict__ dinv,
                                                   const float* __restrict__ b2,
                                                   float* __restrict__ out, int N) {
  int t = blockIdx.x * blockDim.x + threadIdx.x;
  int node = t >> 5, lane = t & 31;
  if (node >= N) return;
  int beg = row_ptr[node], end = row_ptr[node + 1];
  float a0 = 0.f, a1 = 0.f, a2 = 0.f;
  for (int e = beg + lane; e < end; e += 32) {
    float4 v = *(const float4*)&G2[(size_t)sorted_src[e] * 4];
    a0 += v.x; a1 += v.y; a2 += v.z;
  }
  #pragma unroll
  for (int off = 16; off > 0; off >>= 1) {
    a0 += __shfl_down(a0, off, 32);
    a1 += __shfl_down(a1, off, 32);
    a2 += __shfl_down(a2, off, 32);
  }
  if (lane == 0) {
    float di = dinv[node];
    float4 self = *(const float4*)&G2[(size_t)node * 4];
    out[node * 3 + 0] = di * (a0 + self.x) + b2[0];
    out[node * 3 + 1] = di * (a1 + self.y) + b2[1];
    out[node * 3 + 2] = di * (a2 + self.z) + b2[2];
  }
}

// ---------------- launch ----------------

extern "C" void kernel_launch(void* const* d_in, const int* in_sizes, int n_in,
                              void* d_out, int out_size, void* d_ws, size_t ws_size,
                              hipStream_t stream) {
  const float* features = (const float*)d_in[0];
  const int*   edges    = (const int*)d_in[1];
  const float* W1 = (const float*)d_in[4];
  const float* b1 = (const float*)d_in[5];
  const float* W2 = (const float*)d_in[6];
  const float* b2 = (const float*)d_in[7];
  float* out = (float*)d_out;

  const int N = in_sizes[0] / K_IN;   // 70000
  const int E = in_sizes[1] / 2;      // 2,000,000
  const int* src = edges;
  const int* dst = edges + E;
  const int bw = (N + NB - 1) / NB;   // 137

  char* ws = (char*)d_ws;
  size_t off = 0;
  auto alloc = [&](size_t bytes) {
    void* p = ws + off;
    off += (bytes + 255) & ~(size_t)255;
    return p;
  };
  const int eblocks = (E + EPB - 1) / EPB;   // 245 (must be <= 256 for S1)

  int*    pbc           = (int*)   alloc((size_t)NB * eblocks * sizeof(int));
  int*    bt            = (int*)   alloc((size_t)NB * sizeof(int));
  int*    bucket_base   = (int*)   alloc((size_t)(NB + 1) * sizeof(int));
  int*    row_ptr       = (int*)   alloc((size_t)(N + 1) * sizeof(int));
  float*  dinv          = (float*) alloc((size_t)N * sizeof(float));
  uint*   staging       = (uint*)  alloc((size_t)E * sizeof(uint));
  int*    sorted_src    = (int*)   alloc((size_t)E * sizeof(int));
  ushort* G1            = (ushort*)alloc((size_t)N * N_FEAT * sizeof(ushort));
  float*  G2            = (float*) alloc((size_t)N * 4 * sizeof(float));
  ushort* W1T           = (ushort*)alloc((size_t)N_FEAT * KPAD2 * sizeof(ushort));
  (void)ws_size;

  const int convBlocks = (N_FEAT * KPAD2 + 255) / 256;

  convw1_hist_kernel<<<convBlocks + eblocks, 256, 0, stream>>>(W1, W1T, dst, pbc, E, bw, convBlocks, eblocks);
  csr_scan_bucket_kernel<<<NB, 256, 0, stream>>>(pbc, bt, eblocks);
  csr_bucket_scan_kernel<<<1, 256, 0, stream>>>(bt, bucket_base);
  csr_stage_kernel<<<eblocks, 256, 0, stream>>>(src, dst, pbc, bucket_base, staging, E, bw, eblocks);
  csr_final_kernel<<<NB, 256, 0, stream>>>(staging, bucket_base, row_ptr, sorted_src, dinv, N, bw, E);
  gemm1_mfma_kernel<<<(N + BM - 1) / BM, 256, 0, stream>>>(features, W1T, dinv, G1, N);
  agg1mm_kernel<<<((size_t)N * 64 + 255) / 256, 256, 0, stream>>>(G1, row_ptr, sorted_src, dinv, b1, W2, G2, N);
  agg2_kernel<<<((size_t)N * 32 + 255) / 256, 256, 0, stream>>>(G2, row_ptr, sorted_src, dinv, b2, out, N);
}

// Round 16
// 233.582 us; speedup vs baseline: 1.8560x; 1.0113x over previous
//
#include <hip/hip_runtime.h>
#include <hip/hip_bf16.h>

#define K_IN   1044
#define N_FEAT 128
#define KPAD2  1088   // 17 * 64
#define NST2   17
#define BM     96

#define NB     512    // coarse buckets for counting sort
#define BWMAX  256    // max nodes per bucket (runtime bw = ceil(N/NB) = 137)
#define EPB    8192   // edges per block in hist/stage (eblocks = 245 <= 256!)

typedef __attribute__((ext_vector_type(8))) short short8;
typedef __attribute__((ext_vector_type(4))) float f32x4;

__device__ __forceinline__ ushort f2bf(float f) {
  unsigned x = __float_as_uint(f);
  x += 0x7fffu + ((x >> 16) & 1u);   // round-to-nearest-even
  return (ushort)(x >> 16);
}
// packed pair conversion: compiler lowers to v_cvt_pk_bf16_f32
__device__ __forceinline__ uint pkbf(float lo, float hi) {
  __hip_bfloat162 h = __float22bfloat162_rn(make_float2(lo, hi));
  return *reinterpret_cast<uint*>(&h);
}
__device__ __forceinline__ float bflo(uint v) { return __uint_as_float(v << 16); }
__device__ __forceinline__ float bfhi(uint v) { return __uint_as_float(v & 0xFFFF0000u); }

// exact d/bw for d*bw < 2^32 via M32 = ceil(2^32/bw)
__device__ __forceinline__ uint divbw(uint d, uint M32) { return __umulhi(d, M32); }

// async global->LDS, 16B per lane; dest = wave-uniform base + lane*16 (HW)
__device__ __forceinline__ void gld16(const void* g, void* l) {
  __builtin_amdgcn_global_load_lds(
      (const __attribute__((address_space(1))) unsigned int*)g,
      (__attribute__((address_space(3))) unsigned int*)l, 16, 0, 0);
}

// ================= merged: W1 convert + CSR bucket histogram =================
// blocks [0, convBlocks): W1 -> bf16 transposed [128][KPAD2], chunk-swizzled.
// blocks [convBlocks, ...): per-block bucket histogram of dst -> pbc[bucket][blk].

__global__ __launch_bounds__(256) void convw1_hist_kernel(const float* __restrict__ W1,
                                                          ushort* __restrict__ W1T,
                                                          const int* __restrict__ dst,
                                                          int* __restrict__ pbc,
                                                          int E, int bw, uint M32,
                                                          int convBlocks, int eblocks) {
  if ((int)blockIdx.x < convBlocks) {
    int idx = blockIdx.x * 256 + threadIdx.x;
    if (idx >= N_FEAT * KPAD2) return;
    int col = idx / KPAD2, k = idx - col * KPAD2;
    int kk = k & ~63;
    int jp = (k >> 3) & 7;
    int e  = k & 7;
    int jl = jp ^ (col & 7);
    int ksrc = kk + 8 * jl + e;
    W1T[idx] = (ksrc < K_IN) ? f2bf(W1[(size_t)ksrc * N_FEAT + col]) : (ushort)0;
  } else {
    __shared__ int h[NB];
    const int t = threadIdx.x;
    const int blk = blockIdx.x - convBlocks;
    for (int i = t; i < NB; i += 256) h[i] = 0;
    __syncthreads();
    const int e0 = blk * EPB;
    const int e1 = min(e0 + EPB, E);
    for (int e = e0 + t; e < e1; e += 256) atomicAdd(&h[divbw((uint)dst[e], M32)], 1);
    __syncthreads();
    for (int i = t; i < NB; i += 256) pbc[i * eblocks + blk] = h[i];
  }
}

// S1: one block per bucket: exclusive scan of pbc[b][0..eblocks) in LDS,
// in-place within-bucket prefixes; bucket total -> bt[b].
__global__ __launch_bounds__(256) void csr_scan_bucket_kernel(int* __restrict__ pbc,
                                                              int* __restrict__ bt,
                                                              int eblocks) {
  __shared__ int sc[256];
  const int b = blockIdx.x;
  const int t = threadIdx.x;
  int v = (t < eblocks) ? pbc[(size_t)b * eblocks + t] : 0;
  sc[t] = v;
  __syncthreads();
  for (int off = 1; off < 256; off <<= 1) {
    int x = (t >= off) ? sc[t - off] : 0;
    __syncthreads();
    sc[t] += x;
    __syncthreads();
  }
  if (t < eblocks) pbc[(size_t)b * eblocks + t] = sc[t] - v;   // exclusive
  if (t == 255) bt[b] = sc[255];
}

// staging entry: (src << 8) | (dst - bucket*bw), bw=137 < 256.
// Bucket bases derived locally: LDS scan of bt[NB] + this block's pbc column.
__global__ __launch_bounds__(256) void csr_stage_kernel(const int* __restrict__ src,
                                                        const int* __restrict__ dst,
                                                        const int* __restrict__ pbc,
                                                        const int* __restrict__ bt,
                                                        uint* __restrict__ staging, int E, int bw,
                                                        uint M32, int eblocks) {
  __shared__ int sc[256];
  __shared__ int cur[NB];
  const int t = threadIdx.x;
  const int blk = blockIdx.x;
  int v0 = bt[2 * t], v1 = bt[2 * t + 1];
  int s = v0 + v1;
  sc[t] = s;
  __syncthreads();
  for (int off = 1; off < 256; off <<= 1) {
    int x = (t >= off) ? sc[t - off] : 0;
    __syncthreads();
    sc[t] += x;
    __syncthreads();
  }
  int excl = sc[t] - s;
  cur[2 * t]     = excl      + pbc[(size_t)(2 * t) * eblocks + blk];
  cur[2 * t + 1] = excl + v0 + pbc[(size_t)(2 * t + 1) * eblocks + blk];
  __syncthreads();
  const int e0 = blk * EPB;
  const int e1 = min(e0 + EPB, E);
  for (int e = e0 + t; e < e1; e += 256) {
    int d = dst[e];
    int b = (int)divbw((uint)d, M32);
    int p = atomicAdd(&cur[b], 1);
    staging[p] = ((uint)src[e] << 8) | (uint)(d - b * bw);
  }
}

// one block per bucket: node histogram + scan + scatter -> row_ptr, sorted_src, dinv.
// Bucket base derived locally from bt (LDS scan).
__global__ __launch_bounds__(256) void csr_final_kernel(const uint* __restrict__ staging,
                                                        const int* __restrict__ bt,
                                                        int* __restrict__ row_ptr,
                                                        int* __restrict__ sorted_src,
                                                        float* __restrict__ dinv,
                                                        int N, int bw, int E) {
  __shared__ int hist[BWMAX];
  __shared__ int sc[256];
  __shared__ int bb[NB];
  const int b = blockIdx.x;
  const int t = threadIdx.x;
  if (b == 0 && t == 0) row_ptr[N] = E;

  // exclusive scan of bt -> bb (bucket bases)
  {
    int v0 = bt[2 * t], v1 = bt[2 * t + 1];
    int s = v0 + v1;
    sc[t] = s;
    __syncthreads();
    for (int off = 1; off < 256; off <<= 1) {
      int x = (t >= off) ? sc[t - off] : 0;
      __syncthreads();
      sc[t] += x;
      __syncthreads();
    }
    int excl = sc[t] - s;
    bb[2 * t]     = excl;
    bb[2 * t + 1] = excl + v0;
    __syncthreads();
  }

  const int node0 = b * bw;
  const int nn = min(bw, N - node0);
  if (nn <= 0) return;
  const int base = bb[b];
  const int cnt  = bt[b];

  for (int i = t; i < BWMAX; i += 256) hist[i] = 0;
  __syncthreads();
  for (int i = t; i < cnt; i += 256)
    atomicAdd(&hist[staging[base + i] & 255u], 1);
  __syncthreads();
  int v = (t < nn) ? hist[t] : 0;
  if (t < nn) dinv[node0 + t] = rsqrtf((float)(v + 1));   // +1 self-loop
  sc[t] = v;
  __syncthreads();
  for (int off = 1; off < 256; off <<= 1) {
    int x = (t >= off) ? sc[t - off] : 0;
    __syncthreads();
    sc[t] += x;
    __syncthreads();
  }
  int excl = sc[t] - v;
  if (t < nn) row_ptr[node0 + t] = base + excl;
  if (t < nn) hist[t] = excl;   // reuse as cursors
  __syncthreads();
  for (int i = t; i < cnt; i += 256) {
    uint p = staging[base + i];
    int c = atomicAdd(&hist[p & 255u], 1);
    sorted_src[base + c] = (int)(p >> 8);
  }
}

// ---------------- layer 1 GEMM (MFMA bf16): g1 = dinv * (X @ W1), stored bf16 ----------------
// BM=96, BN=128, BK=64 staging; 4 waves (2x2), wave tile 48x64.
// Both tiles via global_load_lds, double-buffered, one __syncthreads per stage.

__global__ __launch_bounds__(256) void gemm1_mfma_kernel(const float* __restrict__ X,
                                                         const ushort* __restrict__ W1T,
                                                         const float* __restrict__ dinv,
                                                         ushort* __restrict__ G1, int M) {
  __shared__ float  Af[2][BM * 64];      // 2 x 24 KB
  __shared__ ushort Bsb[2][128 * 64];    // 2 x 16 KB   (total 80 KB -> 2 blocks/CU)

  const int t = threadIdx.x;
  const int row0 = blockIdx.x * BM;
  const int w = t >> 6, l = t & 63;
  const int w24 = w * 24, w32 = w * 32;
  const int Mm1 = M - 1;

  const int wm = w >> 1, wn = w & 1;
  const int lr = l & 15, g = l >> 4;

  f32x4 acc[3][4] = {};

  auto stage = [&](int s, int buf) {
    const int kk = s * 64;
    #pragma unroll
    for (int i = 0; i < 6; i++) {
      int r  = w24 + 4 * i + (l >> 4);
      int jl = (l & 15) ^ (r & 15);
      int grow = min(row0 + r, Mm1);
      int gk   = min(kk + 4 * jl, K_IN - 4);
      gld16(X + (size_t)grow * K_IN + gk, (void*)&Af[buf][(w24 + 4 * i) * 64]);
    }
    #pragma unroll
    for (int i = 0; i < 4; i++) {
      int c = w32 + 8 * i + (l >> 3);
      gld16(W1T + (size_t)c * KPAD2 + kk + 8 * (l & 7),
            (void*)&Bsb[buf][(w32 + 8 * i) * 64]);
    }
  };

  stage(0, 0);
  __syncthreads();

  int cur = 0;
  #pragma unroll 1
  for (int s = 0; s < NST2; s++) {
    if (s + 1 < NST2) stage(s + 1, cur ^ 1);   // async into other buffer

    #pragma unroll
    for (int ss = 0; ss < 2; ss++) {
      short8 af[3], bfr[4];
      #pragma unroll
      for (int m = 0; m < 3; m++) {
        const int row = wm * 48 + m * 16 + lr;
        const float* rp = &Af[cur][row * 64];
        const int c0 = (ss * 8 + 2 * g)     ^ (row & 15);
        const int c1 = (ss * 8 + 2 * g + 1) ^ (row & 15);
        float4 a0 = *(const float4*)&rp[c0 * 4];
        float4 a1 = *(const float4*)&rp[c1 * 4];
        uint4 uu = make_uint4(pkbf(a0.x, a0.y), pkbf(a0.z, a0.w),
                              pkbf(a1.x, a1.y), pkbf(a1.z, a1.w));
        af[m] = *(short8*)&uu;
      }
      #pragma unroll
      for (int n = 0; n < 4; n++) {
        const int col = wn * 64 + n * 16 + lr;
        const int cB = (ss * 4 + g) ^ (col & 7);
        bfr[n] = *(const short8*)&Bsb[cur][col * 64 + cB * 8];
      }
      #pragma unroll
      for (int m = 0; m < 3; m++)
        #pragma unroll
        for (int n = 0; n < 4; n++)
          acc[m][n] = __builtin_amdgcn_mfma_f32_16x16x32_bf16(af[m], bfr[n], acc[m][n], 0, 0, 0);
    }

    __syncthreads();   // next stage landed; reads of cur done
    cur ^= 1;
  }

  const int rbase = row0 + wm * 48 + g * 4;
  const int cbase = wn * 64 + lr;
  #pragma unroll
  for (int m = 0; m < 3; m++) {
    #pragma unroll
    for (int r = 0; r < 4; r++) {
      int row = rbase + m * 16 + r;
      if (row < M) {
        float dv = dinv[row];
        #pragma unroll
        for (int n = 0; n < 4; n++)
          G1[(size_t)row * N_FEAT + cbase + n * 16] = f2bf(dv * acc[m][n][r]);
      }
    }
  }
}

// ---------------- fused layer-1 aggregation + layer-2 GEMM ----------------

__global__ __launch_bounds__(256) void agg1mm_kernel(const ushort* __restrict__ G1,
                                                     const int* __restrict__ row_ptr,
                                                     const int* __restrict__ sorted_src,
                                                     const float* __restrict__ dinv,
                                                     const float* __restrict__ b1,
                                                     const float* __restrict__ W2,  // [128][3]
                                                     float* __restrict__ G2, int N) {
  const int w = (blockIdx.x * blockDim.x + threadIdx.x) >> 6;   // node
  const int lane = threadIdx.x & 63;
  if (w >= N) return;
  const int beg = row_ptr[w], end = row_ptr[w + 1];
  const uint* g1u = (const uint*)G1;
  const int co = lane;

  uint vs = g1u[((size_t)w << 6) + co];
  float a0 = bflo(vs), a1 = bfhi(vs);

  int e = beg;
  for (; e + 16 <= end; e += 16) {
    int s[16];
    #pragma unroll
    for (int i = 0; i < 16; i++) s[i] = sorted_src[e + i];
    uint v[16];
    #pragma unroll
    for (int i = 0; i < 16; i++) v[i] = g1u[((size_t)s[i] << 6) + co];
    #pragma unroll
    for (int i = 0; i < 16; i++) { a0 += bflo(v[i]); a1 += bfhi(v[i]); }
  }
  for (; e + 4 <= end; e += 4) {
    int s[4];
    #pragma unroll
    for (int i = 0; i < 4; i++) s[i] = sorted_src[e + i];
    uint v[4];
    #pragma unroll
    for (int i = 0; i < 4; i++) v[i] = g1u[((size_t)s[i] << 6) + co];
    #pragma unroll
    for (int i = 0; i < 4; i++) { a0 += bflo(v[i]); a1 += bfhi(v[i]); }
  }
  for (; e < end; e++) {
    uint v = g1u[((size_t)sorted_src[e] << 6) + co];
    a0 += bflo(v); a1 += bfhi(v);
  }

  const float di = dinv[w];
  float r0 = fmaxf(fmaf(di, a0, b1[2 * co + 0]), 0.f);
  float r1 = fmaxf(fmaf(di, a1, b1[2 * co + 1]), 0.f);

  const float* wrow = W2 + 6 * co;
  float s0 = r0 * wrow[0] + r1 * wrow[3];
  float s1 = r0 * wrow[1] + r1 * wrow[4];
  float s2 = r0 * wrow[2] + r1 * wrow[5];
  #pragma unroll
  for (int off = 32; off > 0; off >>= 1) {
    s0 += __shfl_down(s0, off);
    s1 += __shfl_down(s1, off);
    s2 += __shfl_down(s2, off);
  }
  if (lane == 0) {
    *(float4*)&G2[(size_t)w * 4] = make_float4(di * s0, di * s1, di * s2, 0.f);
  }
}

// ---------------- layer 2 aggregation: 4 nodes per wave (16 lanes each) ----------------

__global__ __launch_bounds__(256) void agg2_kernel(const float* __restrict__ G2,  // [N][4]
                                                   const int* __restrict__ row_ptr,
                                                   const int* __restrict__ sorted_src,
                                                   const float* __restrict__ dinv,
                                                   const float* __restrict__ b2,
                                                   float* __restrict__ out, int N) {
  int t = blockIdx.x * blockDim.x + threadIdx.x;
  int node = t >> 4, lane = t & 15;
  if (node >= N) return;
  int beg = row_ptr[node], end = row_ptr[node + 1];
  float a0 = 0.f, a1 = 0.f, a2 = 0.f;
  for (int e = beg + lane; e < end; e += 16) {
    float4 v = *(const float4*)&G2[(size_t)sorted_src[e] * 4];
    a0 += v.x; a1 += v.y; a2 += v.z;
  }
  #pragma unroll
  for (int off = 8; off > 0; off >>= 1) {
    a0 += __shfl_down(a0, off, 16);
    a1 += __shfl_down(a1, off, 16);
    a2 += __shfl_down(a2, off, 16);
  }
  if (lane == 0) {
    float di = dinv[node];
    float4 self = *(const float4*)&G2[(size_t)node * 4];
    out[node * 3 + 0] = di * (a0 + self.x) + b2[0];
    out[node * 3 + 1] = di * (a1 + self.y) + b2[1];
    out[node * 3 + 2] = di * (a2 + self.z) + b2[2];
  }
}

// ---------------- launch ----------------

extern "C" void kernel_launch(void* const* d_in, const int* in_sizes, int n_in,
                              void* d_out, int out_size, void* d_ws, size_t ws_size,
                              hipStream_t stream) {
  const float* features = (const float*)d_in[0];
  const int*   edges    = (const int*)d_in[1];
  const float* W1 = (const float*)d_in[4];
  const float* b1 = (const float*)d_in[5];
  const float* W2 = (const float*)d_in[6];
  const float* b2 = (const float*)d_in[7];
  float* out = (float*)d_out;

  const int N = in_sizes[0] / K_IN;   // 70000
  const int E = in_sizes[1] / 2;      // 2,000,000
  const int* src = edges;
  const int* dst = edges + E;
  const int bw = (N + NB - 1) / NB;   // 137
  const uint M32 = (uint)((0x100000000ULL + (unsigned long long)bw - 1) / (unsigned long long)bw);

  char* ws = (char*)d_ws;
  size_t off = 0;
  auto alloc = [&](size_t bytes) {
    void* p = ws + off;
    off += (bytes + 255) & ~(size_t)255;
    return p;
  };
  const int eblocks = (E + EPB - 1) / EPB;   // 245 (must be <= 256 for S1)

  int*    pbc           = (int*)   alloc((size_t)NB * eblocks * sizeof(int));
  int*    bt            = (int*)   alloc((size_t)NB * sizeof(int));
  int*    row_ptr       = (int*)   alloc((size_t)(N + 1) * sizeof(int));
  float*  dinv          = (float*) alloc((size_t)N * sizeof(float));
  uint*   staging       = (uint*)  alloc((size_t)E * sizeof(uint));
  int*    sorted_src    = (int*)   alloc((size_t)E * sizeof(int));
  ushort* G1            = (ushort*)alloc((size_t)N * N_FEAT * sizeof(ushort));
  float*  G2            = (float*) alloc((size_t)N * 4 * sizeof(float));
  ushort* W1T           = (ushort*)alloc((size_t)N_FEAT * KPAD2 * sizeof(ushort));
  (void)ws_size;

  const int convBlocks = (N_FEAT * KPAD2 + 255) / 256;

  convw1_hist_kernel<<<convBlocks + eblocks, 256, 0, stream>>>(W1, W1T, dst, pbc, E, bw, M32, convBlocks, eblocks);
  csr_scan_bucket_kernel<<<NB, 256, 0, stream>>>(pbc, bt, eblocks);
  csr_stage_kernel<<<eblocks, 256, 0, stream>>>(src, dst, pbc, bt, staging, E, bw, M32, eblocks);
  csr_final_kernel<<<NB, 256, 0, stream>>>(staging, bt, row_ptr, sorted_src, dinv, N, bw, E);
  gemm1_mfma_kernel<<<(N + BM - 1) / BM, 256, 0, stream>>>(features, W1T, dinv, G1, N);
  agg1mm_kernel<<<((size_t)N * 64 + 255) / 256, 256, 0, stream>>>(G1, row_ptr, sorted_src, dinv, b1, W2, G2, N);
  agg2_kernel<<<((size_t)N * 16 + 255) / 256, 256, 0, stream>>>(G2, row_ptr, sorted_src, dinv, b2, out, N);
}